// Round 6
// baseline (278.951 us; speedup 1.0000x reference)
//
#include <hip/hip_runtime.h>
#include <math.h>

typedef __attribute__((ext_vector_type(8))) short short8;
typedef __attribute__((ext_vector_type(4))) short short4v;
typedef __attribute__((ext_vector_type(4))) float f32x4;

constexpr int BLOCK = 1024;
constexpr int B_ = 4, C_ = 64, N_ = 32768, K_ = 16;
constexpr int P_ = 32;            // points per tile -> 96 cols (col = k*32 + p)
constexpr int XS  = 96;           // xa row stride (shorts): ci 0..67 valid, 68..95 zero
constexpr int H1S = 128;          // h1 row stride: 128 co
constexpr int H2S = 64;           // h2 row stride: 64 co
constexpr int NFRAG = 48;         // 24 (L1) + 16 (L2) + 8 (L3)
constexpr int TPB = 16;           // tiles per persistent block

// round-to-nearest-even split: f = hi_bf16 + lo_bf16 (+O(2^-17 rel))
__device__ __forceinline__ void bf16split(float f, short &hi, short &lo) {
    unsigned u  = __builtin_bit_cast(unsigned, f);
    unsigned hb = (u + 0x7FFFu + ((u >> 16) & 1u)) & 0xFFFF0000u;
    float hf    = __builtin_bit_cast(float, hb);
    hi = (short)(hb >> 16);
    float lf    = f - hf;                       // exact
    unsigned ul = __builtin_bit_cast(unsigned, lf);
    lo = (short)((ul + 0x7FFFu + ((ul >> 16) & 1u)) >> 16);
}

__device__ __forceinline__ f32x4 mm(short8 a, short8 b, f32x4 c) {
    return __builtin_amdgcn_mfma_f32_16x16x32_bf16(a, b, c, 0, 0, 0);
}

// XOR-swizzled LDS byte address: soff in shorts, col = logical column
__device__ __forceinline__ char* swz(const void* base, int soff, int col) {
    return (char*)base + ((soff << 1) ^ ((col & 7) << 4));
}

// ---------------- prologue: BN-fold + split weights into A-fragment layout ----
__global__ void prep_wfrags(const float* __restrict__ W1, const float* __restrict__ g1,
                            const float* __restrict__ W2, const float* __restrict__ g2,
                            const float* __restrict__ W3, const float* __restrict__ g3,
                            unsigned short* __restrict__ wf)
{
    const int gid = blockIdx.x * 256 + threadIdx.x;   // [0, 3072)
    if (gid >= NFRAG * 64) return;
    const int f = gid >> 6, l = gid & 63;
    const float RS = 1.0f / sqrtf(1.0f + 1e-5f);
    const float *W, *g; int CI, m, ks;
    if (f < 24)      { W = W1; g = g1; CI = 68;  m = f / 3;        ks = f % 3; }
    else if (f < 40) { W = W2; g = g2; CI = 128; m = (f - 24) / 4; ks = (f - 24) % 4; }
    else             { W = W3; g = g3; CI = 64;  m = (f - 40) / 2; ks = (f - 40) % 2; }
    const int co = m * 16 + (l & 15);
    const int kb = ks * 32 + ((l >> 4) << 3);
    const float gs = g[co] * RS;
    short8 h8, l8;
#pragma unroll
    for (int j = 0; j < 8; ++j) {
        const int k = kb + j;
        const float w = (k < CI) ? W[(size_t)co * CI + k] * gs : 0.0f;
        short hi, lo; bf16split(w, hi, lo);
        h8[j] = hi; l8[j] = lo;
    }
    *reinterpret_cast<short8*>(wf + (size_t)(f * 128 + l) * 8)      = h8;
    *reinterpret_cast<short8*>(wf + (size_t)(f * 128 + 64 + l) * 8) = l8;
}

__device__ __forceinline__ void ldfrag(const unsigned short* __restrict__ wf,
                                       int f, int l, short8 &h, short8 &lo) {
    h  = *reinterpret_cast<const short8*>(wf + (size_t)(f * 128 + l) * 8);
    lo = *reinterpret_cast<const short8*>(wf + (size_t)(f * 128 + 64 + l) * 8);
}

// ---- per-tile global loads to registers (issued early) ----
__device__ __forceinline__ void tile_load(const float* __restrict__ feat,
        const float* __restrict__ src, const float* __restrict__ tgt,
        int b, int n0, int tid, float4* pf, float* rl)
{
#pragma unroll
    for (int it = 0; it < 2; ++it) {
        const int idx = tid + it * BLOCK;
        const int c = idx >> 5, p = idx & 31;
        pf[it] = *reinterpret_cast<const float4*>(
            feat + ((size_t)(b * C_ + c) * N_ + (n0 + p)) * K_);
    }
    if (tid < 96) {
        const int p = tid & 31, k = tid >> 5, n = n0 + p;
        rl[0] = src[((size_t)(b*3+0)*N_ + n)*K_ + k];
        rl[1] = src[((size_t)(b*3+1)*N_ + n)*K_ + k];
        rl[2] = src[((size_t)(b*3+2)*N_ + n)*K_ + k];
        rl[3] = tgt[(size_t)(b*3+0)*N_ + n];
        rl[4] = tgt[(size_t)(b*3+1)*N_ + n];
        rl[5] = tgt[(size_t)(b*3+2)*N_ + n];
    }
}

// ---- split + write prefetched tile into (swizzled) xa buffer ----
__device__ __forceinline__ void tile_store(unsigned short* xah, unsigned short* xal,
        int tid, const float4* pf, const float* rl)
{
#pragma unroll
    for (int it = 0; it < 2; ++it) {
        const int idx = tid + it * BLOCK;
        const int c = idx >> 5, p = idx & 31;
        const float v[3] = {pf[it].x, pf[it].y, pf[it].z};
#pragma unroll
        for (int k = 0; k < 3; ++k) {
            short hi, lo; bf16split(v[k], hi, lo);
            const int col = k*32 + p, so = col*XS + c;
            *(unsigned short*)swz(xah, so, col) = (unsigned short)hi;
            *(unsigned short*)swz(xal, so, col) = (unsigned short)lo;
        }
    }
    if (tid < 96) {
        const int p = tid & 31, k = tid >> 5;
        const float d0 = rl[0]-rl[3], d1 = rl[1]-rl[4], d2 = rl[2]-rl[5];
        const float dd[4] = {d0, d1, d2, d0*d0 + d1*d1 + d2*d2};
        const int col = k*32 + p;
#pragma unroll
        for (int j = 0; j < 4; ++j) {
            short hi, lo; bf16split(dd[j], hi, lo);
            const int so = col*XS + 64 + j;
            *(unsigned short*)swz(xah, so, col) = (unsigned short)hi;
            *(unsigned short*)swz(xal, so, col) = (unsigned short)lo;
        }
    }
}

__global__ __launch_bounds__(BLOCK, 1)
void mvp_mfma(const float* __restrict__ src, const float* __restrict__ tgt,
              const float* __restrict__ feat,
              const unsigned short* __restrict__ wf,
              const float* __restrict__ b1, const float* __restrict__ g1, const float* __restrict__ be1,
              const float* __restrict__ b2, const float* __restrict__ g2, const float* __restrict__ be2,
              const float* __restrict__ b3, const float* __restrict__ g3, const float* __restrict__ be3,
              float* __restrict__ out)
{
    __shared__ __align__(16) unsigned short xa_hi[2][96*XS], xa_lo[2][96*XS];  // 36.9 KB x2
    __shared__ __align__(16) unsigned short h1_hi[96*H1S],  h1_lo[96*H1S];     // 24.6 KB x2
    __shared__ __align__(16) unsigned short h2_hi[96*H2S],  h2_lo[96*H2S];     // 12.3 KB x2
    __shared__ float bias1[128], bias2[64], bias3[64];

    const int tid = threadIdx.x;
    const int w   = tid >> 6;
    const int l   = tid & 63;
    const int b   = blockIdx.x >> 6;            // 64 persistent blocks per batch
    const int n00 = (blockIdx.x & 63) << 9;     // 16 tiles x 32 points
    const float RS = 1.0f / sqrtf(1.0f + 1e-5f);

    // ---- one-time setup: zero xa (incl. pad rows), biases, hoist L1 A-frags ----
    {
        short8 z; 
#pragma unroll
        for (int j = 0; j < 8; ++j) z[j] = 0;
        for (int o = tid; o < (2*96*XS)/8; o += BLOCK) {
            reinterpret_cast<short8*>(&xa_hi[0][0])[o] = z;
            reinterpret_cast<short8*>(&xa_lo[0][0])[o] = z;
        }
    }
    if (tid >= 256 && tid < 384) { int c = tid - 256; bias1[c] = b1[c]*(g1[c]*RS) + be1[c]; }
    if (tid >= 384 && tid < 448) { int c = tid - 384; bias2[c] = b2[c]*(g2[c]*RS) + be2[c]; }
    if (tid >= 448 && tid < 512) { int c = tid - 448; bias3[c] = b3[c]*(g3[c]*RS) + be3[c]; }

    const int kq = (l >> 4) << 3;   // fragment k-offset: 0,8,16,24
    const int lr = l & 15;
    const int rq = (l >> 4) << 2;   // C/D row offset

    const int m1 = w >> 1, hh = w & 1;          // L1/L3 wave tiling
    short8 a1h[3], a1l[3];
#pragma unroll
    for (int ks = 0; ks < 3; ++ks) ldfrag(wf, m1*3 + ks, l, a1h[ks], a1l[ks]);

    // ---- prologue: stage tile 0 ----
    float4 pf[2]; float rl[6];
    tile_load(feat, src, tgt, b, n00, tid, pf, rl);
    tile_store(&xa_hi[0][0], &xa_lo[0][0], tid, pf, rl);
    __syncthreads();

#pragma unroll 1
    for (int i = 0; i < TPB; ++i) {
        const int n0  = n00 + i * P_;
        const int cur = i & 1;
        const bool more = (i + 1 < TPB);
        unsigned short* xah = &xa_hi[cur][0];
        unsigned short* xal = &xa_lo[cur][0];

        // 1. issue next tile's global loads (results consumed after L3)
        if (more) tile_load(feat, src, tgt, b, n0 + P_, tid, pf, rl);

        // ================= L1: 68 -> 128 =================
        {
            f32x4 acc[3] = {f32x4{0,0,0,0}, f32x4{0,0,0,0}, f32x4{0,0,0,0}};
#pragma unroll
            for (int ks = 0; ks < 3; ++ks) {
#pragma unroll
                for (int t = 0; t < 3; ++t) {
                    const int col = (2*t + hh)*16 + lr;
                    const int so  = col*XS + ks*32 + kq;
                    const short8 bh = *reinterpret_cast<const short8*>(swz(xah, so, col));
                    const short8 bl = *reinterpret_cast<const short8*>(swz(xal, so, col));
                    acc[t] = mm(a1h[ks], bh, acc[t]);
                    acc[t] = mm(a1l[ks], bh, acc[t]);
                    acc[t] = mm(a1h[ks], bl, acc[t]);
                }
            }
            const int co0 = m1*16 + rq;
            const float4 bb = *reinterpret_cast<const float4*>(&bias1[co0]);
            const float bbv[4] = {bb.x, bb.y, bb.z, bb.w};
#pragma unroll
            for (int t = 0; t < 3; ++t) {
                const int col = (2*t + hh)*16 + lr;
                short4v h4, l4;
#pragma unroll
                for (int r = 0; r < 4; ++r) {
                    const float v = fmaxf(acc[t][r] + bbv[r], 0.0f);
                    short hi, lo; bf16split(v, hi, lo);
                    h4[r] = hi; l4[r] = lo;
                }
                const int so = col*H1S + co0;
                *reinterpret_cast<short4v*>(swz(h1_hi, so, col)) = h4;
                *reinterpret_cast<short4v*>(swz(h1_lo, so, col)) = l4;
            }
        }
        __syncthreads();

        // ================= L2: 128 -> 64 =================
        {
            const int ntile = (w < 8) ? 2 : 1;
            for (int tt = 0; tt < ntile; ++tt) {
                const int t = w + tt*16;               // 0..23
                const int m = t / 6, n = t % 6;
                const int col = n*16 + lr;
                f32x4 acc = {0,0,0,0};
#pragma unroll
                for (int ks = 0; ks < 4; ++ks) {
                    short8 ah, al;
                    ldfrag(wf, 24 + m*4 + ks, l, ah, al);
                    const int so = col*H1S + ks*32 + kq;
                    const short8 bh = *reinterpret_cast<const short8*>(swz(h1_hi, so, col));
                    const short8 bl = *reinterpret_cast<const short8*>(swz(h1_lo, so, col));
                    acc = mm(ah, bh, acc);
                    acc = mm(al, bh, acc);
                    acc = mm(ah, bl, acc);
                }
                const int co0 = m*16 + rq;
                const float4 bb = *reinterpret_cast<const float4*>(&bias2[co0]);
                const float bbv[4] = {bb.x, bb.y, bb.z, bb.w};
                short4v h4, l4;
#pragma unroll
                for (int r = 0; r < 4; ++r) {
                    const float v = fmaxf(acc[r] + bbv[r], 0.0f);
                    short hi, lo; bf16split(v, hi, lo);
                    h4[r] = hi; l4[r] = lo;
                }
                const int so = col*H2S + co0;
                *reinterpret_cast<short4v*>(swz(h2_hi, so, col)) = h4;
                *reinterpret_cast<short4v*>(swz(h2_lo, so, col)) = l4;
            }
        }
        __syncthreads();

        // ================= L3: 64 -> 64, relu + neighbor-sum + store =================
        if (w < 8) {
            short8 ah[2], al[2];
#pragma unroll
            for (int ks = 0; ks < 2; ++ks) ldfrag(wf, 40 + m1*2 + ks, l, ah[ks], al[ks]);
            f32x4 acc[3] = {f32x4{0,0,0,0}, f32x4{0,0,0,0}, f32x4{0,0,0,0}};
#pragma unroll
            for (int ks = 0; ks < 2; ++ks) {
#pragma unroll
                for (int t = 0; t < 3; ++t) {          // t = neighbor k; col = k*32 + p
                    const int col = t*32 + hh*16 + lr;
                    const int so  = col*H2S + ks*32 + kq;
                    const short8 bh = *reinterpret_cast<const short8*>(swz(h2_hi, so, col));
                    const short8 bl = *reinterpret_cast<const short8*>(swz(h2_lo, so, col));
                    acc[t] = mm(ah[ks], bh, acc[t]);
                    acc[t] = mm(al[ks], bh, acc[t]);
                    acc[t] = mm(ah[ks], bl, acc[t]);
                }
            }
            const int co0 = m1*16 + rq;
            const float4 bb = *reinterpret_cast<const float4*>(&bias3[co0]);
            const float bbv[4] = {bb.x, bb.y, bb.z, bb.w};
            const int p = hh*16 + lr;
#pragma unroll
            for (int r = 0; r < 4; ++r) {
                float s = 0.0f;
#pragma unroll
                for (int t = 0; t < 3; ++t) s += fmaxf(acc[t][r] + bbv[r], 0.0f);
                out[(size_t)(b*64 + co0 + r) * N_ + n0 + p] = s;
            }
        }

        // 2. write prefetched tile into alternate buffer (WAR-safe: last read
        //    of xa[cur^1] was before the L1-end barrier of the previous iter)
        if (more) tile_store(&xa_hi[cur ^ 1][0], &xa_lo[cur ^ 1][0], tid, pf, rl);
        __syncthreads();
    }
}

extern "C" void kernel_launch(void* const* d_in, const int* in_sizes, int n_in,
                              void* d_out, int out_size, void* d_ws, size_t ws_size,
                              hipStream_t stream) {
    const float* src  = (const float*)d_in[0];
    const float* tgt  = (const float*)d_in[1];
    const float* feat = (const float*)d_in[2];
    const float* W1 = (const float*)d_in[3];
    const float* b1 = (const float*)d_in[4];
    const float* g1 = (const float*)d_in[5];
    const float* be1= (const float*)d_in[6];
    const float* W2 = (const float*)d_in[7];
    const float* b2 = (const float*)d_in[8];
    const float* g2 = (const float*)d_in[9];
    const float* be2= (const float*)d_in[10];
    const float* W3 = (const float*)d_in[11];
    const float* b3 = (const float*)d_in[12];
    const float* g3 = (const float*)d_in[13];
    const float* be3= (const float*)d_in[14];
    float* out = (float*)d_out;
    unsigned short* wfrag = (unsigned short*)d_ws;   // 96 KB

    prep_wfrags<<<(NFRAG*64 + 255)/256, 256, 0, stream>>>(W1, g1, W2, g2, W3, g3, wfrag);

    const int grid = B_ * (N_ / P_) / TPB;  // 256 persistent blocks (1 per CU)
    mvp_mfma<<<grid, BLOCK, 0, stream>>>(src, tgt, feat, wfrag,
                                         b1, g1, be1, b2, g2, be2, b3, g3, be3, out);
}

// Round 7
// 184.782 us; speedup vs baseline: 1.5096x; 1.5096x over previous
//
#include <hip/hip_runtime.h>
#include <math.h>

typedef __attribute__((ext_vector_type(8))) short short8;
typedef __attribute__((ext_vector_type(4))) short short4v;
typedef __attribute__((ext_vector_type(4))) float f32x4;

constexpr int BLOCK = 512;
constexpr int B_ = 4, C_ = 64, N_ = 32768, K_ = 16;
constexpr int P_ = 16;            // points per block -> 48 cols (col = k*16 + p)
constexpr int NCOL = 48;
// LDS row strides in bf16 elements (16B-aligned rows)
constexpr int XS  = 104;          // xa rows: ci 0..67 valid, 68..95 zero-padded
constexpr int H1S = 136;          // h1 rows: 128 co
constexpr int H2S = 72;           // h2 rows: 64 co
constexpr int NFRAG = 48;         // 24 (L1: 8m x 3ks) + 16 (L2: 4m x 4ks) + 8 (L3: 4m x 2ks)

// round-to-nearest-even split: f = hi_bf16 + lo_bf16 (+O(2^-17 rel))
__device__ __forceinline__ void bf16split(float f, short &hi, short &lo) {
    unsigned u  = __builtin_bit_cast(unsigned, f);
    unsigned hb = (u + 0x7FFFu + ((u >> 16) & 1u)) & 0xFFFF0000u;
    float hf    = __builtin_bit_cast(float, hb);
    hi = (short)(hb >> 16);
    float lf    = f - hf;                       // exact
    unsigned ul = __builtin_bit_cast(unsigned, lf);
    lo = (short)((ul + 0x7FFFu + ((ul >> 16) & 1u)) >> 16);
}

__device__ __forceinline__ f32x4 mm(short8 a, short8 b, f32x4 c) {
    return __builtin_amdgcn_mfma_f32_16x16x32_bf16(a, b, c, 0, 0, 0);
}

// ---------------- prologue: BN-fold + split weights into A-fragment layout ----
__global__ void prep_wfrags(const float* __restrict__ W1, const float* __restrict__ g1,
                            const float* __restrict__ W2, const float* __restrict__ g2,
                            const float* __restrict__ W3, const float* __restrict__ g3,
                            unsigned short* __restrict__ wf)
{
    const int gid = blockIdx.x * 256 + threadIdx.x;   // [0, 3072)
    if (gid >= NFRAG * 64) return;
    const int f = gid >> 6, l = gid & 63;
    const float RS = 1.0f / sqrtf(1.0f + 1e-5f);
    const float *W, *g; int CI, m, ks;
    if (f < 24)      { W = W1; g = g1; CI = 68;  m = f / 3;        ks = f % 3; }
    else if (f < 40) { W = W2; g = g2; CI = 128; m = (f - 24) / 4; ks = (f - 24) % 4; }
    else             { W = W3; g = g3; CI = 64;  m = (f - 40) / 2; ks = (f - 40) % 2; }
    const int co = m * 16 + (l & 15);
    const int kb = ks * 32 + ((l >> 4) << 3);
    const float gs = g[co] * RS;
    short8 h8, l8;
#pragma unroll
    for (int j = 0; j < 8; ++j) {
        const int k = kb + j;
        const float w = (k < CI) ? W[(size_t)co * CI + k] * gs : 0.0f;
        short hi, lo; bf16split(w, hi, lo);
        h8[j] = hi; l8[j] = lo;
    }
    *reinterpret_cast<short8*>(wf + (size_t)(f * 128 + l) * 8)      = h8;
    *reinterpret_cast<short8*>(wf + (size_t)(f * 128 + 64 + l) * 8) = l8;
}

__device__ __forceinline__ void ldfrag(const unsigned short* __restrict__ wf,
                                       int f, int l, short8 &h, short8 &lo) {
    h  = *reinterpret_cast<const short8*>(wf + (size_t)(f * 128 + l) * 8);
    lo = *reinterpret_cast<const short8*>(wf + (size_t)(f * 128 + 64 + l) * 8);
}

__global__ __launch_bounds__(BLOCK, 4)
void mvp_mfma(const float* __restrict__ src, const float* __restrict__ tgt,
              const float* __restrict__ feat,
              const unsigned short* __restrict__ wf,
              const float* __restrict__ b1, const float* __restrict__ g1, const float* __restrict__ be1,
              const float* __restrict__ b2, const float* __restrict__ g2, const float* __restrict__ be2,
              const float* __restrict__ b3, const float* __restrict__ g3, const float* __restrict__ be3,
              float* __restrict__ out)
{
    __shared__ __align__(16) unsigned short xa_hi[NCOL*XS],  xa_lo[NCOL*XS];   // 9.98 KB x2
    __shared__ __align__(16) unsigned short h1_hi[NCOL*H1S], h1_lo[NCOL*H1S];  // 13.1 KB x2
    __shared__ __align__(16) unsigned short h2_hi[NCOL*H2S], h2_lo[NCOL*H2S];  // 6.9 KB x2
    __shared__ float bias1[128], bias2[64], bias3[64];
    // total ~60.9 KB -> 2 blocks/CU

    const int tid = threadIdx.x;
    const int w   = tid >> 6;                    // 8 waves
    const int l   = tid & 63;
    const int b   = blockIdx.x >> 11;            // N_/P_ = 2048 blocks per batch
    const int n0  = (blockIdx.x & 2047) * P_;
    const float RS = 1.0f / sqrtf(1.0f + 1e-5f);

    // ================= staging =================
    // zero xa pad region ci 68..95 (frag k-range reaches 95)
    if (tid < NCOL * 7) {
        const int col = tid / 7, ch = tid % 7;
        *reinterpret_cast<short4v*>(&xa_hi[col*XS + 68 + ch*4]) = short4v{0,0,0,0};
        *reinterpret_cast<short4v*>(&xa_lo[col*XS + 68 + ch*4]) = short4v{0,0,0,0};
    }
    // feature -> ci 0..63 (one aligned float4 per row covers k=0..2)
    for (int idx = tid; idx < C_ * P_; idx += BLOCK) {
        const int c = idx >> 4, p = idx & 15;
        const float4 f = *reinterpret_cast<const float4*>(
            feat + ((size_t)(b*C_ + c) * N_ + (n0 + p)) * K_);
        const float v[3] = {f.x, f.y, f.z};
#pragma unroll
        for (int k = 0; k < 3; ++k) {
            short hi, lo; bf16split(v[k], hi, lo);
            const int off = (k*16 + p) * XS + c;
            xa_hi[off] = (unsigned short)hi; xa_lo[off] = (unsigned short)lo;
        }
    }
    // relation -> ci 64..67
    if (tid < NCOL) {
        const int p = tid & 15, k = tid >> 4;
        const int n = n0 + p;
        float d[4];
        d[0] = src[((size_t)(b*3+0)*N_ + n)*K_ + k] - tgt[(size_t)(b*3+0)*N_ + n];
        d[1] = src[((size_t)(b*3+1)*N_ + n)*K_ + k] - tgt[(size_t)(b*3+1)*N_ + n];
        d[2] = src[((size_t)(b*3+2)*N_ + n)*K_ + k] - tgt[(size_t)(b*3+2)*N_ + n];
        d[3] = d[0]*d[0] + d[1]*d[1] + d[2]*d[2];
        const int col = k*16 + p;
#pragma unroll
        for (int j = 0; j < 4; ++j) {
            short hi, lo; bf16split(d[j], hi, lo);
            xa_hi[col*XS + 64 + j] = (unsigned short)hi;
            xa_lo[col*XS + 64 + j] = (unsigned short)lo;
        }
    }
    if (tid >= 256 && tid < 384) { int c = tid - 256; bias1[c] = b1[c]*(g1[c]*RS) + be1[c]; }
    if (tid >= 384 && tid < 448) { int c = tid - 384; bias2[c] = b2[c]*(g2[c]*RS) + be2[c]; }
    if (tid >= 448 && tid < 512) { int c = tid - 448; bias3[c] = b3[c]*(g3[c]*RS) + be3[c]; }
    __syncthreads();

    const int kq = (l >> 4) << 3;   // fragment k-offset: 0,8,16,24
    const int lr = l & 15;
    const int rq = (l >> 4) << 2;   // C/D row offset

    // ================= L1: 68 -> 128 (wave = m-tile, 3 n-tiles each) =========
    {
        const int m = w;
        short8 ah[3], al[3];
#pragma unroll
        for (int ks = 0; ks < 3; ++ks) ldfrag(wf, m*3 + ks, l, ah[ks], al[ks]);
        f32x4 acc[3] = {f32x4{0,0,0,0}, f32x4{0,0,0,0}, f32x4{0,0,0,0}};
#pragma unroll
        for (int ks = 0; ks < 3; ++ks) {
#pragma unroll
            for (int t = 0; t < 3; ++t) {
                const int col = t*16 + lr;
                const short8 bh = *reinterpret_cast<const short8*>(&xa_hi[col*XS + ks*32 + kq]);
                const short8 bl = *reinterpret_cast<const short8*>(&xa_lo[col*XS + ks*32 + kq]);
                acc[t] = mm(ah[ks], bh, acc[t]);
                acc[t] = mm(al[ks], bh, acc[t]);
                acc[t] = mm(ah[ks], bl, acc[t]);
            }
        }
        const int co0 = m*16 + rq;
        const float4 bb = *reinterpret_cast<const float4*>(&bias1[co0]);
        const float bbv[4] = {bb.x, bb.y, bb.z, bb.w};
#pragma unroll
        for (int t = 0; t < 3; ++t) {
            const int col = t*16 + lr;
            short4v h4, l4;
#pragma unroll
            for (int r = 0; r < 4; ++r) {
                const float v = fmaxf(acc[t][r] + bbv[r], 0.0f);
                short hi, lo; bf16split(v, hi, lo);
                h4[r] = hi; l4[r] = lo;
            }
            *reinterpret_cast<short4v*>(&h1_hi[col*H1S + co0]) = h4;
            *reinterpret_cast<short4v*>(&h1_lo[col*H1S + co0]) = l4;
        }
    }
    __syncthreads();

    // ================= L2: 128 -> 64 (12 tiles over 8 waves) =================
    {
#pragma unroll
        for (int tt = 0; tt < 2; ++tt) {
            const int t = w + tt*8;
            if (t < 12) {
                const int m = t / 3, n = t % 3;
                const int col = n*16 + lr;
                f32x4 acc = {0,0,0,0};
#pragma unroll
                for (int ks = 0; ks < 4; ++ks) {
                    short8 ah, al;
                    ldfrag(wf, 24 + m*4 + ks, l, ah, al);
                    const short8 bh = *reinterpret_cast<const short8*>(&h1_hi[col*H1S + ks*32 + kq]);
                    const short8 bl = *reinterpret_cast<const short8*>(&h1_lo[col*H1S + ks*32 + kq]);
                    acc = mm(ah, bh, acc);
                    acc = mm(al, bh, acc);
                    acc = mm(ah, bl, acc);
                }
                const int co0 = m*16 + rq;
                const float4 bb = *reinterpret_cast<const float4*>(&bias2[co0]);
                const float bbv[4] = {bb.x, bb.y, bb.z, bb.w};
                short4v h4, l4;
#pragma unroll
                for (int r = 0; r < 4; ++r) {
                    const float v = fmaxf(acc[r] + bbv[r], 0.0f);
                    short hi, lo; bf16split(v, hi, lo);
                    h4[r] = hi; l4[r] = lo;
                }
                *reinterpret_cast<short4v*>(&h2_hi[col*H2S + co0]) = h4;
                *reinterpret_cast<short4v*>(&h2_lo[col*H2S + co0]) = l4;
            }
        }
    }
    __syncthreads();

    // ================= L3: 64 -> 64, relu + neighbor-sum + store ==============
    if (w < 4) {
        const int m = w;
        short8 ah[2], al[2];
#pragma unroll
        for (int ks = 0; ks < 2; ++ks) ldfrag(wf, 40 + m*2 + ks, l, ah[ks], al[ks]);
        f32x4 acc[3] = {f32x4{0,0,0,0}, f32x4{0,0,0,0}, f32x4{0,0,0,0}};
#pragma unroll
        for (int ks = 0; ks < 2; ++ks) {
#pragma unroll
            for (int t = 0; t < 3; ++t) {          // t = neighbor k; col = k*16 + p
                const int col = t*16 + lr;
                const short8 bh = *reinterpret_cast<const short8*>(&h2_hi[col*H2S + ks*32 + kq]);
                const short8 bl = *reinterpret_cast<const short8*>(&h2_lo[col*H2S + ks*32 + kq]);
                acc[t] = mm(ah[ks], bh, acc[t]);
                acc[t] = mm(al[ks], bh, acc[t]);
                acc[t] = mm(ah[ks], bl, acc[t]);
            }
        }
        const int co0 = m*16 + rq;
        const float4 bb = *reinterpret_cast<const float4*>(&bias3[co0]);
        const float bbv[4] = {bb.x, bb.y, bb.z, bb.w};
#pragma unroll
        for (int r = 0; r < 4; ++r) {
            float s = 0.0f;
#pragma unroll
            for (int t = 0; t < 3; ++t) s += fmaxf(acc[t][r] + bbv[r], 0.0f);
            out[(size_t)(b*64 + co0 + r) * N_ + n0 + lr] = s;
        }
    }
}

extern "C" void kernel_launch(void* const* d_in, const int* in_sizes, int n_in,
                              void* d_out, int out_size, void* d_ws, size_t ws_size,
                              hipStream_t stream) {
    const float* src  = (const float*)d_in[0];
    const float* tgt  = (const float*)d_in[1];
    const float* feat = (const float*)d_in[2];
    const float* W1 = (const float*)d_in[3];
    const float* b1 = (const float*)d_in[4];
    const float* g1 = (const float*)d_in[5];
    const float* be1= (const float*)d_in[6];
    const float* W2 = (const float*)d_in[7];
    const float* b2 = (const float*)d_in[8];
    const float* g2 = (const float*)d_in[9];
    const float* be2= (const float*)d_in[10];
    const float* W3 = (const float*)d_in[11];
    const float* b3 = (const float*)d_in[12];
    const float* g3 = (const float*)d_in[13];
    const float* be3= (const float*)d_in[14];
    float* out = (float*)d_out;
    unsigned short* wfrag = (unsigned short*)d_ws;   // 96 KB

    prep_wfrags<<<(NFRAG*64 + 255)/256, 256, 0, stream>>>(W1, g1, W2, g2, W3, g3, wfrag);

    const int grid = B_ * (N_ / P_);  // 8192 blocks, 2 resident per CU
    mvp_mfma<<<grid, BLOCK, 0, stream>>>(src, tgt, feat, wfrag,
                                         b1, g1, be1, b2, g2, be2, b3, g3, be3, out);
}